// Round 10
// baseline (904.277 us; speedup 1.0000x reference)
//
#include <hip/hip_runtime.h>
#include <hip/hip_bf16.h>

// Fused: segment_sum(x_l[edge_lit] by sorted edge_clause) -> [msg|h0] @ [W_ih|W_hh]^T + b
//        -> LSTM cell epilogue -> h_new, c_new.
// Structure = round-8 (best measured: 356us) with Phase B replaced by EDGE-PARALLEL
// gather: 32 groups x 16 lanes; group owns a contiguous edge run; ds_add_f32 atomics
// into fp32 msg tile [64][132] (+4-float row pad rotates bank map 4 banks/row);
// independent iterations -> full MLP, no per-clause serial chain, no shfl reduces.
// LDS squeezed to 54,272 B (< 64K sharedMemPerBlock limit; R9's 70,656 B risked
// launch failure): Amsg ALIASES msgF32's low 16KB -- B2 reads fp32 chunks to regs,
// barrier, then writes bf16 tile over them.
// Other proven pieces: native bf16 cvt, rcp/exp2 gates (no IEEE div sequences),
// c0 reg-prefetch, two-pass coalesced epilogue, W prepack, rowptr hoist, dtype detect.
// Reg budget: 64 arch VGPR + 64 acc = 128 -> 4 waves/SIMD (2 blocks/CU) structural cap.

using frag_ab = __attribute__((ext_vector_type(8))) short;  // 8 bf16 (4 VGPRs)
using frag_cd = __attribute__((ext_vector_type(4))) float;  // 4 fp32

__device__ __forceinline__ float bf2f(unsigned short u) {
    union { unsigned u; float f; } v; v.u = ((unsigned)u) << 16; return v.f;
}
__device__ __forceinline__ unsigned short f2bf(float f) {
    __hip_bfloat16 h = __float2bfloat16(f);   // RNE, native cvt on gfx950
    return *reinterpret_cast<unsigned short*>(&h);
}
// sigmoid = rcp(1 + 2^(-x*log2e)); 1 v_exp + 1 v_add + 1 v_rcp, no div sequence.
__device__ __forceinline__ float sigm(float x) {
    return __builtin_amdgcn_rcpf(1.0f + __builtin_amdgcn_exp2f(-1.442695040889f * x));
}
// tanh(x) = 2*sigmoid(2x) - 1; inf-safe (rcp(inf)=0 -> +/-1).
__device__ __forceinline__ float tanh_fast(float x) {
    float s = __builtin_amdgcn_rcpf(1.0f + __builtin_amdgcn_exp2f(-2.885390081777f * x));
    return __builtin_fmaf(2.0f, s, -1.0f);
}
__device__ __forceinline__ frag_ab load8_fp32(const float* p) {
    float4 a = *reinterpret_cast<const float4*>(p);
    float4 b = *reinterpret_cast<const float4*>(p + 4);
    frag_ab r;
    r[0] = (short)f2bf(a.x); r[1] = (short)f2bf(a.y);
    r[2] = (short)f2bf(a.z); r[3] = (short)f2bf(a.w);
    r[4] = (short)f2bf(b.x); r[5] = (short)f2bf(b.y);
    r[6] = (short)f2bf(b.z); r[7] = (short)f2bf(b.w);
    return r;
}

// ws layout
#define WS_BPACK_OFF  0           // 16384 * 16B = 256 KB
#define WS_BIAS_OFF   262144     // 512 * 4B
#define WS_FLAG_OFF   264192     // 4B
#define WS_ROWPTR_OFF 264704     // (n_clause+1) * 4B  (~1.6 MB)

#define EDGE_CAP 512             // LDS-staged edges per block (global fallback beyond)
#define MROW 132                 // fp32 msg tile row stride (16B-aligned, bank-rotating)

// LDS layout (bytes):
//   [0, 33792)      msgF32 fp32 [64][132]; after B2's read-barrier, [0,16384) = Amsg
//   [33792, 50176)  Ah0 bf16 [64][128] swizzled
//   [50176, 52224)  elits
//   [52224, 54272)  eclau
//   [0, 32768)      LDSf fp32 out-staging (post-GEMM reuse)
#define SH_BYTES 54272
#define OFF_AH0  33792
#define OFF_ELIT 50176
#define OFF_ECLA 52224

// Decide device float dtype: sample even-indexed 16-bit words of x_l.
// fp32 -> low mantissa halves (uniform) -> ~25% have exp field >= 0xC0.
// bf16 -> values of N(0,1) -> exp field < 0x90 always.
__global__ void detect_fmt(const unsigned short* __restrict__ x, int* __restrict__ flag) {
    int t = threadIdx.x;
    int cnt = 0;
    for (int i = t; i < 4096; i += 64) {
        unsigned e = (x[2 * i] >> 7) & 0xFF;
        cnt += (e >= 0xC0) ? 1 : 0;
    }
    #pragma unroll
    for (int s = 32; s; s >>= 1) cnt += __shfl_xor(cnt, s);
    if (t == 0) *flag = (cnt > 64) ? 1 : 0;   // 1 = fp32, 0 = bf16
}

// CSR row offsets for every clause (dtype-independent).
__global__ void build_rowptr(const int* __restrict__ edge_clause, int* __restrict__ rowptr,
                             int n_edges, int n_clause) {
    int idx = blockIdx.x * blockDim.x + threadIdx.x;
    if (idx > n_clause) return;
    int lo = 0, hi = n_edges;
    while (lo < hi) {
        int mid = (lo + hi) >> 1;
        if (edge_clause[mid] < idx) lo = mid + 1; else hi = mid;
    }
    rowptr[idx] = lo;
}

// Pack W_ih/W_hh into bf16 Bpack: chunk idx = (kk*512 + n)*4 + lq holds 8 bf16 of
// k = (kk&3)*32 + lq*8 .. +8 from row n of (kk<4 ? W_ih : W_hh). Also bias sum fp32.
template <int FP32IN>
__global__ void prepack(const void* __restrict__ W_ih_, const void* __restrict__ W_hh_,
                        const void* __restrict__ b_ih_, const void* __restrict__ b_hh_,
                        unsigned short* __restrict__ Bpack, float* __restrict__ bias,
                        const int* __restrict__ flag) {
    if (*flag != FP32IN) return;
    int idx = blockIdx.x * blockDim.x + threadIdx.x;
    if (idx < 16384) {
        int kk = idx >> 11;
        int n  = (idx >> 2) & 511;
        int lq = idx & 3;
        int ksrc = (kk & 3) * 32 + lq * 8;
        frag_ab v;
        if constexpr (FP32IN) {
            const float* W = (kk < 4) ? (const float*)W_ih_ : (const float*)W_hh_;
            v = load8_fp32(W + (size_t)n * 128 + ksrc);
        } else {
            const unsigned short* W =
                (kk < 4) ? (const unsigned short*)W_ih_ : (const unsigned short*)W_hh_;
            v = *reinterpret_cast<const frag_ab*>(W + (size_t)n * 128 + ksrc);
        }
        *reinterpret_cast<frag_ab*>(Bpack + (size_t)idx * 8) = v;
    }
    if (idx < 512) {
        float b;
        if constexpr (FP32IN)
            b = ((const float*)b_ih_)[idx] + ((const float*)b_hh_)[idx];
        else
            b = bf2f(((const unsigned short*)b_ih_)[idx]) +
                bf2f(((const unsigned short*)b_hh_)[idx]);
        bias[idx] = b;
    }
}

template <int FP32IN>
__global__ __launch_bounds__(512, 4) void lit2clause_fused(
    const void* __restrict__ x_l_,
    const void* __restrict__ h0_,
    const void* __restrict__ c0_,
    const unsigned short* __restrict__ Bpack,
    const float* __restrict__ bias,
    const int*  __restrict__ rowptr_g,
    const int*  __restrict__ edge_lit,
    const int*  __restrict__ edge_clause,
    void* __restrict__ out_,
    const int* __restrict__ fmt_flag,
    int n_clause)
{
    if (*fmt_flag != FP32IN) return;   // wrong-dtype variant: bail (uniform, pre-barrier)

    __shared__ __align__(16) unsigned char SH[SH_BYTES];
    float* msgF32 = (float*)SH;                       // [64][MROW] fp32
    unsigned char* Amsg = SH;                         // bf16 [64][128] (aliases msgF32)
    unsigned char* Ah0  = SH + OFF_AH0;               // bf16 [64][128] swizzled
    int* elits = (int*)(SH + OFF_ELIT);
    int* eclau = (int*)(SH + OFF_ECLA);
    float* LDSf = (float*)SH;                         // post-GEMM out staging

    const int tid  = threadIdx.x;
    const int lane = tid & 63;
    const int w    = tid >> 6;          // wave 0..7
    const int cbase = blockIdx.x * 64;  // first clause row of this block

    // ---- Phase A: zero msg tile; stage edge indices; h0 tile cvt+stage ----
    const int eBase = rowptr_g[cbase];
    const int eEnd  = rowptr_g[cbase + 64];
    const int eCount = eEnd - eBase;

    for (int q = tid; q < (64 * MROW) / 4; q += 512)
        *reinterpret_cast<float4*>(msgF32 + q * 4) = (float4){0.f, 0.f, 0.f, 0.f};

    for (int i = tid; i < eCount && i < EDGE_CAP; i += 512) {
        elits[i] = edge_lit[eBase + i];
        eclau[i] = edge_clause[eBase + i];
    }

    #pragma unroll
    for (int q0 = 0; q0 < 2; ++q0) {
        int q = tid + q0 * 512;           // 1024 chunks: 64 rows x 16 x (8 values)
        int row = q >> 4;
        int j   = q & 15;
        frag_ab v;
        if constexpr (FP32IN) {
            v = load8_fp32((const float*)h0_ + (size_t)(cbase + row) * 128 + j * 8);
        } else {
            v = *reinterpret_cast<const frag_ab*>(
                (const unsigned short*)h0_ + (size_t)(cbase + row) * 128 + j * 8);
        }
        int byte = (j * 16) ^ ((row & 7) << 4);
        *reinterpret_cast<frag_ab*>(Ah0 + row * 256 + byte) = v;
    }
    __syncthreads();

    // ---- Phase B: EDGE-PARALLEL segment-sum. Group g (16 lanes) owns contiguous
    //      edges [g*len, (g+1)*len); lane l16 covers dims l16*8..+8; ds_add_f32
    //      accumulate into padded fp32 tile. Iterations independent -> full MLP. ----
    {
        const int g   = tid >> 4;         // group 0..31
        const int l16 = tid & 15;
        const int len = (eCount + 31) >> 5;
        const int gStart = g * len;
        for (int i = 0; i < len; ++i) {
            int e = gStart + i;
            if (e >= eCount) break;
            int lit, cl;
            if (e < EDGE_CAP) { lit = elits[e]; cl = eclau[e]; }
            else { lit = edge_lit[eBase + e]; cl = edge_clause[eBase + e]; }
            int row = cl - cbase;
            float* dst = msgF32 + row * MROW + l16 * 8;
            if constexpr (FP32IN) {
                const float* xr = (const float*)x_l_ + (size_t)lit * 128 + l16 * 8;
                float4 v0 = *reinterpret_cast<const float4*>(xr);
                float4 v1 = *reinterpret_cast<const float4*>(xr + 4);
                atomicAdd(dst + 0, v0.x); atomicAdd(dst + 1, v0.y);
                atomicAdd(dst + 2, v0.z); atomicAdd(dst + 3, v0.w);
                atomicAdd(dst + 4, v1.x); atomicAdd(dst + 5, v1.y);
                atomicAdd(dst + 6, v1.z); atomicAdd(dst + 7, v1.w);
            } else {
                const unsigned short* xr =
                    (const unsigned short*)x_l_ + (size_t)lit * 128 + l16 * 8;
                frag_ab v = *reinterpret_cast<const frag_ab*>(xr);
                #pragma unroll
                for (int j = 0; j < 8; ++j)
                    atomicAdd(dst + j, bf2f((unsigned short)v[j]));
            }
        }
    }
    __syncthreads();

    // ---- Phase B2: fp32 msg tile -> swizzled bf16 Amsg (ALIASES msgF32 low 16K):
    //      read chunks to regs, barrier, then write. ----
    float4 rc[2][2];
    #pragma unroll
    for (int q0 = 0; q0 < 2; ++q0) {
        int q = tid + q0 * 512;           // 1024 chunks: 64 rows x 16 x (8 values)
        int row = q >> 4;
        int jj  = q & 15;
        const float* src = msgF32 + row * MROW + jj * 8;
        rc[q0][0] = *reinterpret_cast<const float4*>(src);
        rc[q0][1] = *reinterpret_cast<const float4*>(src + 4);
    }
    __syncthreads();                      // all msgF32 reads done before Amsg overwrite
    #pragma unroll
    for (int q0 = 0; q0 < 2; ++q0) {
        int q = tid + q0 * 512;
        int row = q >> 4;
        int jj  = q & 15;
        frag_ab o;
        o[0] = (short)f2bf(rc[q0][0].x); o[1] = (short)f2bf(rc[q0][0].y);
        o[2] = (short)f2bf(rc[q0][0].z); o[3] = (short)f2bf(rc[q0][0].w);
        o[4] = (short)f2bf(rc[q0][1].x); o[5] = (short)f2bf(rc[q0][1].y);
        o[6] = (short)f2bf(rc[q0][1].z); o[7] = (short)f2bf(rc[q0][1].w);
        int byte = (jj * 16) ^ ((row & 7) << 4);
        *reinterpret_cast<frag_ab*>(Amsg + row * 256 + byte) = o;
    }
    __syncthreads();   // msg + h0 tiles ready

    // ---- Phase C: c0 prefetch (issue early, consume after GEMM), then GEMM ----
    const int l15 = lane & 15;
    const int lq  = lane >> 4;  // 0..3 (k-chunk group)
    const int d = w * 16 + l15;

    float cold[4][4];
    #pragma unroll
    for (int mf = 0; mf < 4; ++mf) {
        #pragma unroll
        for (int r = 0; r < 4; ++r) {
            int m = cbase + mf * 16 + lq * 4 + r;
            if constexpr (FP32IN) cold[mf][r] = ((const float*)c0_)[(size_t)m * 128 + d];
            else cold[mf][r] = bf2f(((const unsigned short*)c0_)[(size_t)m * 128 + d]);
        }
    }

    frag_cd acc[4][4];
    #pragma unroll
    for (int g = 0; g < 4; ++g)
        #pragma unroll
        for (int mf = 0; mf < 4; ++mf)
            acc[g][mf] = (frag_cd){0.f, 0.f, 0.f, 0.f};

    const frag_ab* Bp = reinterpret_cast<const frag_ab*>(Bpack);
    float bi[4];
    #pragma unroll
    for (int g = 0; g < 4; ++g) bi[g] = bias[g * 128 + d];

    #pragma unroll
    for (int kk = 0; kk < 8; ++kk) {             // K = 256, 32 per step
        const unsigned char* At = (kk < 4) ? Amsg : Ah0;
        frag_ab afr[4];
        #pragma unroll
        for (int mf = 0; mf < 4; ++mf) {
            int row = mf * 16 + l15;
            int byte = ((kk & 3) * 64 + lq * 16) ^ ((row & 7) << 4);
            afr[mf] = *reinterpret_cast<const frag_ab*>(At + row * 256 + byte);
        }
        frag_ab bfr[4];
        #pragma unroll
        for (int g = 0; g < 4; ++g) {
            int n = g * 128 + w * 16 + l15;
            bfr[g] = Bp[(kk * 512 + n) * 4 + lq];
        }
        #pragma unroll
        for (int g = 0; g < 4; ++g)
            #pragma unroll
            for (int mf = 0; mf < 4; ++mf)
                acc[g][mf] = __builtin_amdgcn_mfma_f32_16x16x32_bf16(
                    afr[mf], bfr[g], acc[g][mf], 0, 0, 0);
    }

    // ---- Phase D: LSTM gate math (wave-local; c0 already in regs; rcp/exp2) ----
    #pragma unroll
    for (int mf = 0; mf < 4; ++mf) {
        #pragma unroll
        for (int r = 0; r < 4; ++r) {
            float gi = acc[0][mf][r] + bi[0];
            float gf = acc[1][mf][r] + bi[1];
            float gg = acc[2][mf][r] + bi[2];
            float go = acc[3][mf][r] + bi[3];
            float iv = sigm(gi);
            float fv = sigm(gf);
            float gv = tanh_fast(gg);
            float ov = sigm(go);
            float cn = fv * cold[mf][r] + iv * gv;
            float hn = ov * tanh_fast(cn);
            acc[0][mf][r] = hn;
            acc[1][mf][r] = cn;
        }
    }

    // ---- Phase E: stage h/c through 32K LDS (chunk-XOR swizzle), two passes,
    //      flush full-line coalesced. Swizzle: float4-chunk c' = c ^ (row&7). ----
    #pragma unroll
    for (int half = 0; half < 2; ++half) {       // 0 = h_new, 1 = c_new
        __syncthreads();                         // prior LDS use done
        #pragma unroll
        for (int mf = 0; mf < 4; ++mf) {
            #pragma unroll
            for (int r = 0; r < 4; ++r) {
                int rl = mf * 16 + lq * 4 + r;
                int idx = rl * 128 + ((((d >> 2) ^ (rl & 7)) << 2) | (d & 3));
                LDSf[idx] = acc[half][mf][r];
            }
        }
        __syncthreads();
        if constexpr (FP32IN) {
            float* outp = (float*)out_ + (size_t)half * n_clause * 128;
            #pragma unroll
            for (int q0 = 0; q0 < 4; ++q0) {
                int q = tid + q0 * 512;          // 2048 float4 chunks
                int row = q >> 5;
                int j   = q & 31;
                float4 v = *reinterpret_cast<const float4*>(
                    &LDSf[row * 128 + ((j ^ (row & 7)) << 2)]);
                *reinterpret_cast<float4*>(outp + (size_t)(cbase + row) * 128 + j * 4) = v;
            }
        } else {
            unsigned short* outp = (unsigned short*)out_ + (size_t)half * n_clause * 128;
            #pragma unroll
            for (int q0 = 0; q0 < 2; ++q0) {
                int q = tid + q0 * 512;          // 1024 chunks of 8 values
                int row = q >> 4;
                int jj  = q & 15;
                int j0 = 2 * jj, j1 = 2 * jj + 1;
                float4 f0 = *reinterpret_cast<const float4*>(
                    &LDSf[row * 128 + ((j0 ^ (row & 7)) << 2)]);
                float4 f1 = *reinterpret_cast<const float4*>(
                    &LDSf[row * 128 + ((j1 ^ (row & 7)) << 2)]);
                frag_ab o;
                o[0] = (short)f2bf(f0.x); o[1] = (short)f2bf(f0.y);
                o[2] = (short)f2bf(f0.z); o[3] = (short)f2bf(f0.w);
                o[4] = (short)f2bf(f1.x); o[5] = (short)f2bf(f1.y);
                o[6] = (short)f2bf(f1.z); o[7] = (short)f2bf(f1.w);
                *reinterpret_cast<frag_ab*>(outp + (size_t)(cbase + row) * 128 + jj * 8) = o;
            }
        }
    }
}

extern "C" void kernel_launch(void* const* d_in, const int* in_sizes, int n_in,
                              void* d_out, int out_size, void* d_ws, size_t ws_size,
                              hipStream_t stream) {
    const void* x_l  = d_in[0];
    const void* h0   = d_in[1];
    const void* c0   = d_in[2];
    const void* W_ih = d_in[3];
    const void* W_hh = d_in[4];
    const void* b_ih = d_in[5];
    const void* b_hh = d_in[6];
    const int* edge_lit    = (const int*)d_in[7];
    const int* edge_clause = (const int*)d_in[8];

    int n_edges  = in_sizes[7];
    int n_clause = in_sizes[1] / 128;       // 400000
    int nblocks  = (n_clause + 63) / 64;    // 6250 exact

    unsigned char* ws = (unsigned char*)d_ws;
    unsigned short* Bpack = (unsigned short*)(ws + WS_BPACK_OFF);
    float* bias  = (float*)(ws + WS_BIAS_OFF);
    int* flag    = (int*)(ws + WS_FLAG_OFF);
    int* rowptr  = (int*)(ws + WS_ROWPTR_OFF);

    detect_fmt<<<1, 64, 0, stream>>>((const unsigned short*)x_l, flag);

    build_rowptr<<<(n_clause + 256) / 256, 256, 0, stream>>>(
        edge_clause, rowptr, n_edges, n_clause);

    prepack<1><<<64, 256, 0, stream>>>(W_ih, W_hh, b_ih, b_hh, Bpack, bias, flag);
    prepack<0><<<64, 256, 0, stream>>>(W_ih, W_hh, b_ih, b_hh, Bpack, bias, flag);

    lit2clause_fused<1><<<nblocks, 512, 0, stream>>>(
        x_l, h0, c0, Bpack, bias, rowptr, edge_lit, edge_clause, d_out, flag, n_clause);
    lit2clause_fused<0><<<nblocks, 512, 0, stream>>>(
        x_l, h0, c0, Bpack, bias, rowptr, edge_lit, edge_clause, d_out, flag, n_clause);
}

// Round 11
// 367.358 us; speedup vs baseline: 2.4616x; 2.4616x over previous
//
#include <hip/hip_runtime.h>
#include <hip/hip_bf16.h>

// Split design (round 11):
//   k1 gather_msg: segment-sum x_l[edge_lit] -> msg (bf16) into the C-HALF of d_out
//      (scratch; each row is later overwritten by the same block's c_new in k2).
//      No GEMM registers -> __launch_bounds__(512,8) -> 8 waves/SIMD (2x the fused
//      kernel's 4) to hide the gather's dependent-load latency chains.
//   k2 gemm_lstm: stage msg+h0 coalesced -> swizzled LDS tiles -> MFMA GEMM vs
//      prepacked W -> LSTM epilogue (rcp/exp2) -> h/c via two-pass coalesced LDS flush.
// msg row i at byte i*(FP32?512:256) in c-half: row-for-row aliasing with c_new ->
// block-local read-before-write, no cross-block hazard; k1 completes before k2 (stream).
// Proven pieces kept: R8 quarter-wave gather + xor-reduce, native bf16 cvt, rcp/exp2
// gates, c0 reg-prefetch, two-pass coalesced epilogue, W prepack, rowptr hoist,
// runtime dtype detect (both template variants launch; wrong one exits on flag).

using frag_ab = __attribute__((ext_vector_type(8))) short;  // 8 bf16 (4 VGPRs)
using frag_cd = __attribute__((ext_vector_type(4))) float;  // 4 fp32

__device__ __forceinline__ float bf2f(unsigned short u) {
    union { unsigned u; float f; } v; v.u = ((unsigned)u) << 16; return v.f;
}
__device__ __forceinline__ unsigned short f2bf(float f) {
    __hip_bfloat16 h = __float2bfloat16(f);   // RNE, native cvt on gfx950
    return *reinterpret_cast<unsigned short*>(&h);
}
// sigmoid = rcp(1 + 2^(-x*log2e)); 1 v_exp + 1 v_add + 1 v_rcp, no div sequence.
__device__ __forceinline__ float sigm(float x) {
    return __builtin_amdgcn_rcpf(1.0f + __builtin_amdgcn_exp2f(-1.442695040889f * x));
}
// tanh(x) = 2*sigmoid(2x) - 1; inf-safe (rcp(inf)=0 -> +/-1).
__device__ __forceinline__ float tanh_fast(float x) {
    float s = __builtin_amdgcn_rcpf(1.0f + __builtin_amdgcn_exp2f(-2.885390081777f * x));
    return __builtin_fmaf(2.0f, s, -1.0f);
}
__device__ __forceinline__ frag_ab load8_fp32(const float* p) {
    float4 a = *reinterpret_cast<const float4*>(p);
    float4 b = *reinterpret_cast<const float4*>(p + 4);
    frag_ab r;
    r[0] = (short)f2bf(a.x); r[1] = (short)f2bf(a.y);
    r[2] = (short)f2bf(a.z); r[3] = (short)f2bf(a.w);
    r[4] = (short)f2bf(b.x); r[5] = (short)f2bf(b.y);
    r[6] = (short)f2bf(b.z); r[7] = (short)f2bf(b.w);
    return r;
}

// ws layout
#define WS_BPACK_OFF  0           // 16384 * 16B = 256 KB
#define WS_BIAS_OFF   262144     // 512 * 4B
#define WS_FLAG_OFF   264192     // 4B
#define WS_ROWPTR_OFF 264704     // (n_clause+1) * 4B  (~1.6 MB)

#define EDGE_CAP 512             // LDS-staged edges per block (global fallback beyond)

// Decide device float dtype: sample even-indexed 16-bit words of x_l.
// fp32 -> low mantissa halves (uniform) -> ~25% have exp field >= 0xC0.
// bf16 -> values of N(0,1) -> exp field < 0x90 always.
__global__ void detect_fmt(const unsigned short* __restrict__ x, int* __restrict__ flag) {
    int t = threadIdx.x;
    int cnt = 0;
    for (int i = t; i < 4096; i += 64) {
        unsigned e = (x[2 * i] >> 7) & 0xFF;
        cnt += (e >= 0xC0) ? 1 : 0;
    }
    #pragma unroll
    for (int s = 32; s; s >>= 1) cnt += __shfl_xor(cnt, s);
    if (t == 0) *flag = (cnt > 64) ? 1 : 0;   // 1 = fp32, 0 = bf16
}

// CSR row offsets for every clause (dtype-independent).
__global__ void build_rowptr(const int* __restrict__ edge_clause, int* __restrict__ rowptr,
                             int n_edges, int n_clause) {
    int idx = blockIdx.x * blockDim.x + threadIdx.x;
    if (idx > n_clause) return;
    int lo = 0, hi = n_edges;
    while (lo < hi) {
        int mid = (lo + hi) >> 1;
        if (edge_clause[mid] < idx) lo = mid + 1; else hi = mid;
    }
    rowptr[idx] = lo;
}

// Pack W_ih/W_hh into bf16 Bpack: chunk idx = (kk*512 + n)*4 + lq holds 8 bf16 of
// k = (kk&3)*32 + lq*8 .. +8 from row n of (kk<4 ? W_ih : W_hh). Also bias sum fp32.
template <int FP32IN>
__global__ void prepack(const void* __restrict__ W_ih_, const void* __restrict__ W_hh_,
                        const void* __restrict__ b_ih_, const void* __restrict__ b_hh_,
                        unsigned short* __restrict__ Bpack, float* __restrict__ bias,
                        const int* __restrict__ flag) {
    if (*flag != FP32IN) return;
    int idx = blockIdx.x * blockDim.x + threadIdx.x;
    if (idx < 16384) {
        int kk = idx >> 11;
        int n  = (idx >> 2) & 511;
        int lq = idx & 3;
        int ksrc = (kk & 3) * 32 + lq * 8;
        frag_ab v;
        if constexpr (FP32IN) {
            const float* W = (kk < 4) ? (const float*)W_ih_ : (const float*)W_hh_;
            v = load8_fp32(W + (size_t)n * 128 + ksrc);
        } else {
            const unsigned short* W =
                (kk < 4) ? (const unsigned short*)W_ih_ : (const unsigned short*)W_hh_;
            v = *reinterpret_cast<const frag_ab*>(W + (size_t)n * 128 + ksrc);
        }
        *reinterpret_cast<frag_ab*>(Bpack + (size_t)idx * 8) = v;
    }
    if (idx < 512) {
        float b;
        if constexpr (FP32IN)
            b = ((const float*)b_ih_)[idx] + ((const float*)b_hh_)[idx];
        else
            b = bf2f(((const unsigned short*)b_ih_)[idx]) +
                bf2f(((const unsigned short*)b_hh_)[idx]);
        bias[idx] = b;
    }
}

// ---- k1: segment-sum gather -> bf16 msg rows in the c-half of d_out (scratch).
//      R8's proven quarter-wave-per-edge scheme; high occupancy (8 waves/SIMD). ----
template <int FP32IN>
__global__ __launch_bounds__(512, 8) void gather_msg(
    const void* __restrict__ x_l_,
    const int*  __restrict__ rowptr_g,
    const int*  __restrict__ edge_lit,
    void* __restrict__ out_,
    const int* __restrict__ fmt_flag,
    int n_clause)
{
    if (*fmt_flag != FP32IN) return;

    __shared__ int elits[EDGE_CAP];
    const int tid  = threadIdx.x;
    const int lane = tid & 63;
    const int w    = tid >> 6;
    const int cbase = blockIdx.x * 64;

    unsigned short* msgb;
    if constexpr (FP32IN) msgb = (unsigned short*)((float*)out_ + (size_t)n_clause * 128);
    else                  msgb = (unsigned short*)out_ + (size_t)n_clause * 128;
    constexpr int MSTRIDE = FP32IN ? 256 : 128;   // shorts per msg row (aliases c rows 1:1)

    int rp_l = 0;
    if (lane < 9) rp_l = rowptr_g[cbase + w * 8 + lane];
    const int eBase = rowptr_g[cbase];
    const int eEnd  = rowptr_g[cbase + 64];
    const int eCount = eEnd - eBase;
    for (int i = tid; i < eCount && i < EDGE_CAP; i += 512)
        elits[i] = edge_lit[eBase + i];
    __syncthreads();

    const int q   = lane >> 4;    // quarter 0..3 -> edge e = st + q + 4*i
    const int l16 = lane & 15;    // 8 values per lane
    for (int s = 0; s < 8; ++s) {
        int st = __shfl(rp_l, s)     - eBase;
        int en = __shfl(rp_l, s + 1) - eBase;
        float a[8] = {0.f, 0.f, 0.f, 0.f, 0.f, 0.f, 0.f, 0.f};
        for (int e = st + q; e < en; e += 4) {
            int lit = (e < EDGE_CAP) ? elits[e] : edge_lit[eBase + e];
            if constexpr (FP32IN) {
                const float* xr = (const float*)x_l_ + (size_t)lit * 128 + l16 * 8;
                float4 v0 = *reinterpret_cast<const float4*>(xr);
                float4 v1 = *reinterpret_cast<const float4*>(xr + 4);
                a[0] += v0.x; a[1] += v0.y; a[2] += v0.z; a[3] += v0.w;
                a[4] += v1.x; a[5] += v1.y; a[6] += v1.z; a[7] += v1.w;
            } else {
                const unsigned short* xr =
                    (const unsigned short*)x_l_ + (size_t)lit * 128 + l16 * 8;
                frag_ab v = *reinterpret_cast<const frag_ab*>(xr);
                #pragma unroll
                for (int j = 0; j < 8; ++j) a[j] += bf2f((unsigned short)v[j]);
            }
        }
        #pragma unroll
        for (int j = 0; j < 8; ++j) {
            a[j] += __shfl_xor(a[j], 16);
            a[j] += __shfl_xor(a[j], 32);
        }
        if (q == 0) {
            frag_ab o;
            #pragma unroll
            for (int j = 0; j < 8; ++j) o[j] = (short)f2bf(a[j]);
            *reinterpret_cast<frag_ab*>(
                msgb + (size_t)(cbase + w * 8 + s) * MSTRIDE + l16 * 8) = o;
        }
    }
}

// ---- k2: stage msg+h0 -> swizzled LDS, MFMA GEMM vs prepacked W, LSTM epilogue. ----
template <int FP32IN>
__global__ __launch_bounds__(512, 4) void gemm_lstm(
    const void* __restrict__ h0_,
    const void* __restrict__ c0_,
    const unsigned short* __restrict__ Bpack,
    const float* __restrict__ bias,
    void* __restrict__ out_,
    const int* __restrict__ fmt_flag,
    int n_clause)
{
    if (*fmt_flag != FP32IN) return;

    // SH: [Amsg 16K | Ah0 16K] bf16 [64][128], 256B/row, XOR swizzle byte^=(row&7)<<4.
    // Reused post-GEMM as fp32 [64][128] out-staging (two passes: h then c).
    __shared__ __align__(16) unsigned char SH[32768];
    unsigned char* Amsg = SH;
    unsigned char* Ah0  = SH + 16384;
    float* LDSf = (float*)SH;

    const int tid  = threadIdx.x;
    const int lane = tid & 63;
    const int w    = tid >> 6;          // wave 0..7
    const int cbase = blockIdx.x * 64;  // first clause row of this block

    unsigned short* msgb;
    if constexpr (FP32IN) msgb = (unsigned short*)((float*)out_ + (size_t)n_clause * 128);
    else                  msgb = (unsigned short*)out_ + (size_t)n_clause * 128;
    constexpr int MSTRIDE = FP32IN ? 256 : 128;

    // ---- Phase A: stage msg (bf16 copy) + h0 (cvt) into swizzled tiles; one barrier ----
    #pragma unroll
    for (int q0 = 0; q0 < 2; ++q0) {
        int q = tid + q0 * 512;           // 1024 chunks: 64 rows x 16 x (8 values)
        int row = q >> 4;
        int j   = q & 15;
        frag_ab v = *reinterpret_cast<const frag_ab*>(
            msgb + (size_t)(cbase + row) * MSTRIDE + j * 8);
        int byte = (j * 16) ^ ((row & 7) << 4);
        *reinterpret_cast<frag_ab*>(Amsg + row * 256 + byte) = v;
    }
    #pragma unroll
    for (int q0 = 0; q0 < 2; ++q0) {
        int q = tid + q0 * 512;
        int row = q >> 4;
        int j   = q & 15;
        frag_ab v;
        if constexpr (FP32IN) {
            v = load8_fp32((const float*)h0_ + (size_t)(cbase + row) * 128 + j * 8);
        } else {
            v = *reinterpret_cast<const frag_ab*>(
                (const unsigned short*)h0_ + (size_t)(cbase + row) * 128 + j * 8);
        }
        int byte = (j * 16) ^ ((row & 7) << 4);
        *reinterpret_cast<frag_ab*>(Ah0 + row * 256 + byte) = v;
    }
    __syncthreads();

    // ---- Phase C: c0 prefetch (issue early, consume after GEMM), then GEMM ----
    const int l15 = lane & 15;
    const int lq  = lane >> 4;  // 0..3 (k-chunk group)
    const int d = w * 16 + l15;

    float cold[4][4];
    #pragma unroll
    for (int mf = 0; mf < 4; ++mf) {
        #pragma unroll
        for (int r = 0; r < 4; ++r) {
            int m = cbase + mf * 16 + lq * 4 + r;
            if constexpr (FP32IN) cold[mf][r] = ((const float*)c0_)[(size_t)m * 128 + d];
            else cold[mf][r] = bf2f(((const unsigned short*)c0_)[(size_t)m * 128 + d]);
        }
    }

    frag_cd acc[4][4];
    #pragma unroll
    for (int g = 0; g < 4; ++g)
        #pragma unroll
        for (int mf = 0; mf < 4; ++mf)
            acc[g][mf] = (frag_cd){0.f, 0.f, 0.f, 0.f};

    const frag_ab* Bp = reinterpret_cast<const frag_ab*>(Bpack);
    float bi[4];
    #pragma unroll
    for (int g = 0; g < 4; ++g) bi[g] = bias[g * 128 + d];

    #pragma unroll
    for (int kk = 0; kk < 8; ++kk) {             // K = 256, 32 per step
        const unsigned char* At = (kk < 4) ? Amsg : Ah0;
        frag_ab afr[4];
        #pragma unroll
        for (int mf = 0; mf < 4; ++mf) {
            int row = mf * 16 + l15;
            int byte = ((kk & 3) * 64 + lq * 16) ^ ((row & 7) << 4);
            afr[mf] = *reinterpret_cast<const frag_ab*>(At + row * 256 + byte);
        }
        frag_ab bfr[4];
        #pragma unroll
        for (int g = 0; g < 4; ++g) {
            int n = g * 128 + w * 16 + l15;
            bfr[g] = Bp[(kk * 512 + n) * 4 + lq];
        }
        #pragma unroll
        for (int g = 0; g < 4; ++g)
            #pragma unroll
            for (int mf = 0; mf < 4; ++mf)
                acc[g][mf] = __builtin_amdgcn_mfma_f32_16x16x32_bf16(
                    afr[mf], bfr[g], acc[g][mf], 0, 0, 0);
    }

    // ---- Phase D: LSTM gate math (wave-local; c0 already in regs; rcp/exp2) ----
    #pragma unroll
    for (int mf = 0; mf < 4; ++mf) {
        #pragma unroll
        for (int r = 0; r < 4; ++r) {
            float gi = acc[0][mf][r] + bi[0];
            float gf = acc[1][mf][r] + bi[1];
            float gg = acc[2][mf][r] + bi[2];
            float go = acc[3][mf][r] + bi[3];
            float iv = sigm(gi);
            float fv = sigm(gf);
            float gv = tanh_fast(gg);
            float ov = sigm(go);
            float cn = fv * cold[mf][r] + iv * gv;
            float hn = ov * tanh_fast(cn);
            acc[0][mf][r] = hn;
            acc[1][mf][r] = cn;
        }
    }

    // ---- Phase E: stage h/c through 32K LDS (chunk-XOR swizzle), two passes,
    //      flush full-line coalesced. Swizzle: float4-chunk c' = c ^ (row&7). ----
    #pragma unroll
    for (int half = 0; half < 2; ++half) {       // 0 = h_new, 1 = c_new
        __syncthreads();                         // prior LDS use done
        #pragma unroll
        for (int mf = 0; mf < 4; ++mf) {
            #pragma unroll
            for (int r = 0; r < 4; ++r) {
                int rl = mf * 16 + lq * 4 + r;
                int idx = rl * 128 + ((((d >> 2) ^ (rl & 7)) << 2) | (d & 3));
                LDSf[idx] = acc[half][mf][r];
            }
        }
        __syncthreads();
        if constexpr (FP32IN) {
            float* outp = (float*)out_ + (size_t)half * n_clause * 128;
            #pragma unroll
            for (int q0 = 0; q0 < 4; ++q0) {
                int q = tid + q0 * 512;          // 2048 float4 chunks
                int row = q >> 5;
                int j   = q & 31;
                float4 v = *reinterpret_cast<const float4*>(
                    &LDSf[row * 128 + ((j ^ (row & 7)) << 2)]);
                *reinterpret_cast<float4*>(outp + (size_t)(cbase + row) * 128 + j * 4) = v;
            }
        } else {
            unsigned short* outp = (unsigned short*)out_ + (size_t)half * n_clause * 128;
            #pragma unroll
            for (int q0 = 0; q0 < 2; ++q0) {
                int q = tid + q0 * 512;          // 1024 chunks of 8 values
                int row = q >> 4;
                int jj  = q & 15;
                int j0 = 2 * jj, j1 = 2 * jj + 1;
                float4 f0 = *reinterpret_cast<const float4*>(
                    &LDSf[row * 128 + ((j0 ^ (row & 7)) << 2)]);
                float4 f1 = *reinterpret_cast<const float4*>(
                    &LDSf[row * 128 + ((j1 ^ (row & 7)) << 2)]);
                frag_ab o;
                o[0] = (short)f2bf(f0.x); o[1] = (short)f2bf(f0.y);
                o[2] = (short)f2bf(f0.z); o[3] = (short)f2bf(f0.w);
                o[4] = (short)f2bf(f1.x); o[5] = (short)f2bf(f1.y);
                o[6] = (short)f2bf(f1.z); o[7] = (short)f2bf(f1.w);
                *reinterpret_cast<frag_ab*>(outp + (size_t)(cbase + row) * 128 + jj * 8) = o;
            }
        }
    }
}

extern "C" void kernel_launch(void* const* d_in, const int* in_sizes, int n_in,
                              void* d_out, int out_size, void* d_ws, size_t ws_size,
                              hipStream_t stream) {
    const void* x_l  = d_in[0];
    const void* h0   = d_in[1];
    const void* c0   = d_in[2];
    const void* W_ih = d_in[3];
    const void* W_hh = d_in[4];
    const void* b_ih = d_in[5];
    const void* b_hh = d_in[6];
    const int* edge_lit    = (const int*)d_in[7];
    const int* edge_clause = (const int*)d_in[8];

    int n_edges  = in_sizes[7];
    int n_clause = in_sizes[1] / 128;       // 400000
    int nblocks  = (n_clause + 63) / 64;    // 6250 exact

    unsigned char* ws = (unsigned char*)d_ws;
    unsigned short* Bpack = (unsigned short*)(ws + WS_BPACK_OFF);
    float* bias  = (float*)(ws + WS_BIAS_OFF);
    int* flag    = (int*)(ws + WS_FLAG_OFF);
    int* rowptr  = (int*)(ws + WS_ROWPTR_OFF);

    detect_fmt<<<1, 64, 0, stream>>>((const unsigned short*)x_l, flag);

    build_rowptr<<<(n_clause + 256) / 256, 256, 0, stream>>>(
        edge_clause, rowptr, n_edges, n_clause);

    prepack<1><<<64, 256, 0, stream>>>(W_ih, W_hh, b_ih, b_hh, Bpack, bias, flag);
    prepack<0><<<64, 256, 0, stream>>>(W_ih, W_hh, b_ih, b_hh, Bpack, bias, flag);

    gather_msg<1><<<nblocks, 512, 0, stream>>>(
        x_l, rowptr, edge_lit, d_out, flag, n_clause);
    gather_msg<0><<<nblocks, 512, 0, stream>>>(
        x_l, rowptr, edge_lit, d_out, flag, n_clause);

    gemm_lstm<1><<<nblocks, 512, 0, stream>>>(
        h0, c0, Bpack, bias, d_out, flag, n_clause);
    gemm_lstm<0><<<nblocks, 512, 0, stream>>>(
        h0, c0, Bpack, bias, d_out, flag, n_clause);
}